// Round 5
// baseline (125.822 us; speedup 1.0000x reference)
//
#include <hip/hip_runtime.h>

#define B_    1
#define N_    6
#define C_    80
#define D_    112
#define HF_   16
#define WF_   44
#define NX_   128
#define NY_   128
#define NZ_   1
#define HW_   (HF_ * WF_)          // 704
#define NPIX_ (NZ_ * NX_ * NY_)    // 16384
#define CAMHW_ (N_ * HW_)          // 4224
#define ENTCAP_ (HW_ * N_ * D_)    // 473088 worst-case entries

// ---------------- 3x3 inverse (adjugate) ----------------
__device__ __forceinline__ void inv3(const float* m, float* o) {
    float a = m[0], b = m[1], c = m[2];
    float d = m[3], e = m[4], f = m[5];
    float g = m[6], h = m[7], i = m[8];
    float A  =  (e * i - f * h);
    float Bc = -(d * i - f * g);
    float Cc =  (d * h - e * g);
    float det = a * A + b * Bc + c * Cc;
    float id = 1.0f / det;
    o[0] = A * id;                  o[1] = -(b * i - c * h) * id;   o[2] =  (b * f - c * e) * id;
    o[3] = Bc * id;                 o[4] =  (a * i - c * g) * id;   o[5] = -(a * f - c * d) * id;
    o[6] = Cc * id;                 o[7] = -(a * h - b * g) * id;   o[8] =  (a * e - b * d) * id;
}

__device__ __forceinline__ int voxel_of(float xs, float ys, float dv, const float* sm) {
    const float* ip  = sm;       // invPost
    const float* cmb = sm + 9;   // rots @ inv(intrins)
    float ptx = sm[18], pty = sm[19], ptz = sm[20];
    float trx = sm[21], trY = sm[22], trz = sm[23];
    float p0x = xs - ptx, p0y = ys - pty, p0z = dv - ptz;
    float p1x = ip[0]*p0x + ip[1]*p0y + ip[2]*p0z;
    float p1y = ip[3]*p0x + ip[4]*p0y + ip[5]*p0z;
    float p1z = ip[6]*p0x + ip[7]*p0y + ip[8]*p0z;
    float qx = p1x * p1z, qy = p1y * p1z, qz = p1z;
    float rx = cmb[0]*qx + cmb[1]*qy + cmb[2]*qz + trx;
    float ry = cmb[3]*qx + cmb[4]*qy + cmb[5]*qz + trY;
    float rz = cmb[6]*qx + cmb[7]*qy + cmb[8]*qz + trz;
    const float lox = -50.8f - 0.4f;   // bx - dx/2, f32 fold matches np
    const float loy = -50.8f - 0.4f;
    const float loz = -10.0f;
    int ix = (int)((rx - lox) / 0.8f);   // trunc toward zero == astype(int32)
    int iy = (int)((ry - loy) / 0.8f);
    int iz = (int)((rz - loz) / 20.0f);
    bool val = (ix >= 0) && (ix < NX_) && (iy >= 0) && (iy < NY_) && (iz >= 0) && (iz < NZ_);
    return val ? ((iz * NX_ + ix) * NY_ + iy) : -1;
}

// ===== Phase A: per-(h,w) softmax + geometry + run-merge, emit entries =====
// entry.x = (cam*HW_+hw) << 14 | vox ; entry.y = weight bits
__global__ __launch_bounds__(256) void runs_kernel(
    const float* __restrict__ rots, const float* __restrict__ trans,
    const float* __restrict__ intrins, const float* __restrict__ post_rots,
    const float* __restrict__ post_trans,
    const float* __restrict__ depth_digit,
    int2* __restrict__ entries, int* __restrict__ gE)
{
    const int hw = blockIdx.x;
    const int w  = hw % WF_;
    const int h  = hw / WF_;
    const int tid  = threadIdx.x;
    const int lane = tid & 63;
    const int wave = tid >> 6;

    __shared__ float s_prob[N_][D_];
    __shared__ short s_vox[N_][D_];
    __shared__ short s_runv[N_][D_];
    __shared__ float s_runw[N_][D_];
    __shared__ float s_mat[N_][24];
    __shared__ int   s_cnt[N_];
    __shared__ int   s_pref[N_ + 1];
    __shared__ int   s_base;

    for (int i = tid; i < N_ * D_; i += 256) {
        int cam = i / D_, d = i - cam * D_;
        s_prob[cam][d] = depth_digit[((size_t)cam * D_ + d) * HW_ + hw];
    }
    if (tid < N_) {
        float ipv[9], ii[9];
        inv3(post_rots + tid * 9, ipv);
        inv3(intrins + tid * 9, ii);
        const float* ro = rots + tid * 9;
        #pragma unroll
        for (int k = 0; k < 9; ++k) s_mat[tid][k] = ipv[k];
        #pragma unroll
        for (int r = 0; r < 3; ++r)
            #pragma unroll
            for (int c = 0; c < 3; ++c)
                s_mat[tid][9 + r * 3 + c] = ro[r*3+0]*ii[0*3+c] + ro[r*3+1]*ii[1*3+c] + ro[r*3+2]*ii[2*3+c];
        #pragma unroll
        for (int k = 0; k < 3; ++k) { s_mat[tid][18+k] = post_trans[tid*3+k]; s_mat[tid][21+k] = trans[tid*3+k]; }
    }
    __syncthreads();

    // softmax per camera (wave handles a camera; lanes 0..55 hold 2 bins)
    for (int cc = wave; cc < N_; cc += 4) {
        bool act = lane < 56;
        float l0 = act ? s_prob[cc][lane]      : -INFINITY;
        float l1 = act ? s_prob[cc][lane + 56] : -INFINITY;
        float m = fmaxf(l0, l1);
        #pragma unroll
        for (int o = 32; o > 0; o >>= 1) m = fmaxf(m, __shfl_xor(m, o));
        float e0 = act ? __expf(l0 - m) : 0.0f;
        float e1 = act ? __expf(l1 - m) : 0.0f;
        float s = e0 + e1;
        #pragma unroll
        for (int o = 32; o > 0; o >>= 1) s += __shfl_xor(s, o);
        float inv = 1.0f / s;
        if (act) { s_prob[cc][lane] = e0 * inv; s_prob[cc][lane + 56] = e1 * inv; }
    }

    // geometry
    {
        float xs = (float)((double)w * (703.0 / 43.0));  // np.linspace(0,703,44)
        float ys = (float)h * 17.0f;                     // np.linspace(0,255,16)
        for (int i = tid; i < N_ * D_; i += 256) {
            int cam = i / D_, d = i - cam * D_;
            float dval = 2.0f + 0.5f * (float)d;
            s_vox[cam][d] = (short)voxel_of(xs, ys, dval, s_mat[cam]);
        }
    }
    __syncthreads();

    // run-length merge per camera (6 threads)
    if (tid < N_) {
        int cnt = 0, last = -1;
        float wsum = 0.0f;
        for (int d = 0; d < D_; ++d) {
            int v = s_vox[tid][d];
            if (v < 0) continue;
            if (v == last) { wsum += s_prob[tid][d]; }
            else {
                if (last >= 0) { s_runv[tid][cnt] = (short)last; s_runw[tid][cnt] = wsum; ++cnt; }
                last = v; wsum = s_prob[tid][d];
            }
        }
        if (last >= 0) { s_runv[tid][cnt] = (short)last; s_runw[tid][cnt] = wsum; ++cnt; }
        s_cnt[tid] = cnt;
    }
    __syncthreads();

    if (tid == 0) {
        int acc = 0;
        #pragma unroll
        for (int cam = 0; cam < N_; ++cam) { s_pref[cam] = acc; acc += s_cnt[cam]; }
        s_pref[N_] = acc;
        s_base = atomicAdd(gE, acc);
    }
    __syncthreads();

    int total = s_pref[N_];
    int base = s_base;
    for (int k = tid; k < total; k += 256) {
        int cam = 0;
        #pragma unroll
        for (int cc = 1; cc < N_; ++cc) if (k >= s_pref[cc]) cam = cc;
        int r = k - s_pref[cam];
        int key = ((cam * HW_ + hw) << 14) | (int)s_runv[cam][r];
        entries[base + k] = make_int2(key, __float_as_int(s_runw[cam][r]));
    }
}

// ===== Phase B: one block per channel; LDS BEV plane accumulation =====
__global__ __launch_bounds__(1024) void accum_kernel(
    const float* __restrict__ img_feat,
    const int2* __restrict__ entries, const int* __restrict__ gE,
    float* __restrict__ outp)
{
    const int c   = blockIdx.x;       // channel
    const int tid = threadIdx.x;

    __shared__ float s_plane[NPIX_];      // 64 KB
    __shared__ float s_feat[CAMHW_];      // 16.5 KB: feat[cam][c][hw]
    __shared__ int   s_E;

    float4* p4 = (float4*)s_plane;
    #pragma unroll
    for (int i = tid; i < NPIX_ / 4; i += 1024) p4[i] = make_float4(0.f, 0.f, 0.f, 0.f);
    for (int i = tid; i < CAMHW_; i += 1024) {
        int cam = i / HW_, hw = i - cam * HW_;
        s_feat[i] = img_feat[((size_t)cam * C_ + c) * HW_ + hw];
    }
    if (tid == 0) s_E = *gE;
    __syncthreads();

    int E = s_E;
    for (int i = tid; i < E; i += 1024) {
        int2 e = entries[i];
        int vox   = e.x & (NPIX_ - 1);
        int camhw = e.x >> 14;
        atomicAdd(&s_plane[vox], __int_as_float(e.y) * s_feat[camhw]);
    }
    __syncthreads();

    float4* o4 = (float4*)(outp + (size_t)c * NPIX_);
    #pragma unroll
    for (int i = tid; i < NPIX_ / 4; i += 1024) o4[i] = p4[i];
}

// ===================== fallback (round-4 proven, needs no ws) =====================
__global__ __launch_bounds__(256) void scatter_merged(
    const float* __restrict__ rots, const float* __restrict__ trans,
    const float* __restrict__ intrins, const float* __restrict__ post_rots,
    const float* __restrict__ post_trans,
    const float* __restrict__ img_feat, const float* __restrict__ depth_digit,
    float* __restrict__ outp)
{
    const int hw = blockIdx.x;
    const int w  = hw % WF_;
    const int h  = hw / WF_;
    const int tid  = threadIdx.x;
    const int lane = tid & 63;
    const int wave = tid >> 6;

    __shared__ float s_prob[N_][D_];
    __shared__ float s_feat[N_][C_];
    __shared__ short s_vox[N_][D_];
    __shared__ short s_runv[N_][D_];
    __shared__ float s_runw[N_][D_];
    __shared__ float s_mat[N_][24];
    __shared__ int   s_cnt[N_];

    for (int i = tid; i < N_ * D_; i += 256) {
        int cam = i / D_, d = i - cam * D_;
        s_prob[cam][d] = depth_digit[((size_t)cam * D_ + d) * HW_ + hw];
    }
    for (int i = tid; i < N_ * C_; i += 256) {
        int cam = i / C_, cc = i - cam * C_;
        s_feat[cam][cc] = img_feat[((size_t)cam * C_ + cc) * HW_ + hw];
    }
    if (tid < N_) {
        float ipv[9], ii[9];
        inv3(post_rots + tid * 9, ipv);
        inv3(intrins + tid * 9, ii);
        const float* ro = rots + tid * 9;
        #pragma unroll
        for (int k = 0; k < 9; ++k) s_mat[tid][k] = ipv[k];
        #pragma unroll
        for (int r = 0; r < 3; ++r)
            #pragma unroll
            for (int c = 0; c < 3; ++c)
                s_mat[tid][9 + r * 3 + c] = ro[r*3+0]*ii[0*3+c] + ro[r*3+1]*ii[1*3+c] + ro[r*3+2]*ii[2*3+c];
        #pragma unroll
        for (int k = 0; k < 3; ++k) { s_mat[tid][18+k] = post_trans[tid*3+k]; s_mat[tid][21+k] = trans[tid*3+k]; }
    }
    __syncthreads();

    for (int cc = wave; cc < N_; cc += 4) {
        bool act = lane < 56;
        float l0 = act ? s_prob[cc][lane]      : -INFINITY;
        float l1 = act ? s_prob[cc][lane + 56] : -INFINITY;
        float m = fmaxf(l0, l1);
        #pragma unroll
        for (int o = 32; o > 0; o >>= 1) m = fmaxf(m, __shfl_xor(m, o));
        float e0 = act ? __expf(l0 - m) : 0.0f;
        float e1 = act ? __expf(l1 - m) : 0.0f;
        float s = e0 + e1;
        #pragma unroll
        for (int o = 32; o > 0; o >>= 1) s += __shfl_xor(s, o);
        float inv = 1.0f / s;
        if (act) { s_prob[cc][lane] = e0 * inv; s_prob[cc][lane + 56] = e1 * inv; }
    }
    {
        float xs = (float)((double)w * (703.0 / 43.0));
        float ys = (float)h * 17.0f;
        for (int i = tid; i < N_ * D_; i += 256) {
            int cam = i / D_, d = i - cam * D_;
            float dval = 2.0f + 0.5f * (float)d;
            s_vox[cam][d] = (short)voxel_of(xs, ys, dval, s_mat[cam]);
        }
    }
    __syncthreads();
    if (tid < N_) {
        int cnt = 0, last = -1;
        float wsum = 0.0f;
        for (int d = 0; d < D_; ++d) {
            int v = s_vox[tid][d];
            if (v < 0) continue;
            if (v == last) { wsum += s_prob[tid][d]; }
            else {
                if (last >= 0) { s_runv[tid][cnt] = (short)last; s_runw[tid][cnt] = wsum; ++cnt; }
                last = v; wsum = s_prob[tid][d];
            }
        }
        if (last >= 0) { s_runv[tid][cnt] = (short)last; s_runw[tid][cnt] = wsum; ++cnt; }
        s_cnt[tid] = cnt;
    }
    __syncthreads();
    for (int cam = 0; cam < N_; ++cam) {
        int cnt = s_cnt[cam];
        int total = cnt * C_;
        for (int k = tid; k < total; k += 256) {
            int r = k / C_;
            int c = k - r * C_;
            int v = s_runv[cam][r];
            atomicAdd(&outp[(size_t)c * NPIX_ + v], s_runw[cam][r] * s_feat[cam][c]);
        }
    }
}

extern "C" void kernel_launch(void* const* d_in, const int* in_sizes, int n_in,
                              void* d_out, int out_size, void* d_ws, size_t ws_size,
                              hipStream_t stream) {
    const float* rots        = (const float*)d_in[1];
    const float* trans       = (const float*)d_in[2];
    const float* intrins     = (const float*)d_in[3];
    const float* post_rots   = (const float*)d_in[4];
    const float* post_trans  = (const float*)d_in[5];
    const float* img_feat    = (const float*)d_in[6];
    const float* depth_digit = (const float*)d_in[7];
    float* outp = (float*)d_out;

    const size_t gE_b      = 256;
    const size_t entries_b = (size_t)ENTCAP_ * 8;
    const size_t need = gE_b + entries_b;

    if (ws_size >= need) {
        int*  gE      = (int*)d_ws;
        int2* entries = (int2*)((char*)d_ws + gE_b);
        hipMemsetAsync(gE, 0, 4, stream);
        runs_kernel<<<HW_, 256, 0, stream>>>(rots, trans, intrins, post_rots, post_trans,
                                             depth_digit, entries, gE);
        accum_kernel<<<C_, 1024, 0, stream>>>(img_feat, entries, gE, outp);
    } else {
        hipMemsetAsync(outp, 0, (size_t)out_size * sizeof(float), stream);
        scatter_merged<<<HW_, 256, 0, stream>>>(rots, trans, intrins, post_rots, post_trans,
                                                img_feat, depth_digit, outp);
    }
}